// Round 1
// baseline (187.721 us; speedup 1.0000x reference)
//
#include <hip/hip_runtime.h>
#include <math.h>

#define CDIM 1024
#define TC   3072
#define BATCH 8
#define NTOK 2049   // N+1 with class token
#define NIN  2048
#define NHEAD 4

// workspace float offsets
#define OFF_Q0 0          // 1024 floats (zeroed)
#define OFF_OC 1024       // 8192 floats (zeroed)
#define ZERO_FLOATS 9216
#define OFF_CK 9216       // 4 floats
#define OFF_WS 9728       // 4*1024 floats, [h][c]
#define OFF_SC 13824      // 8*4*2049 floats, [b][h][n] (scores -> att in place)
#define OFF_YP 79392      // 8*32*4*1024 floats, partial y

// ---- q0 partial: q0[j] = sum_i t[i] * Wqkv[i, j]  (bias added later) ----
__global__ void k_q0(const float* __restrict__ t, const float* __restrict__ W,
                     float* __restrict__ wsb) {
    int ic = blockIdx.x >> 3, jc = blockIdx.x & 7;
    int j = jc * 128 + threadIdx.x;
    int i0 = ic * 128;
    float acc = 0.f;
    for (int i = 0; i < 128; ++i)
        acc += t[i0 + i] * W[(size_t)(i0 + i) * TC + j];
    atomicAdd(&wsb[OFF_Q0 + j], acc);
}

// ---- Ws[h][c] = sum_d Wk[c, h*256+d] * q0full[h*256+d];  ck[h] = bk_h . q0full_h ----
__global__ void k_ws(const float* __restrict__ W, const float* __restrict__ bqkv,
                     float* __restrict__ wsb) {
    int wave = threadIdx.x >> 6, lane = threadIdx.x & 63;
    int gw = blockIdx.x * 4 + wave;        // 4096 waves total
    int c = gw >> 2, h = gw & 3;
    int d0 = h * 256 + lane * 4;
    float4 wv = *(const float4*)&W[(size_t)c * TC + CDIM + d0];
    float q0 = wsb[OFF_Q0 + d0]     + bqkv[d0];
    float q1 = wsb[OFF_Q0 + d0 + 1] + bqkv[d0 + 1];
    float q2 = wsb[OFF_Q0 + d0 + 2] + bqkv[d0 + 2];
    float q3 = wsb[OFF_Q0 + d0 + 3] + bqkv[d0 + 3];
    float acc = wv.x * q0 + wv.y * q1 + wv.z * q2 + wv.w * q3;
    float ck = 0.f;
    bool doCk = (blockIdx.x == 0);          // these waves have c==0, h=0..3
    if (doCk) {
        float4 bk = *(const float4*)&bqkv[CDIM + d0];
        ck = bk.x * q0 + bk.y * q1 + bk.z * q2 + bk.w * q3;
    }
    for (int off = 32; off > 0; off >>= 1) {
        acc += __shfl_down(acc, off);
        ck  += __shfl_down(ck, off);
    }
    if (lane == 0) {
        wsb[OFF_WS + h * CDIM + c] = acc;
        if (doCk) wsb[OFF_CK + h] = ck;
    }
}

// ---- scores[b][h][n] = (x_row . Ws[h] + ck[h]) / 16 ;  one wave per row ----
__global__ __launch_bounds__(1024) void k_scores(const float* __restrict__ x,
                                                 const float* __restrict__ t,
                                                 float* __restrict__ wsb) {
    __shared__ float WsL[4 * CDIM];
    __shared__ float ckL[4];
    for (int i = threadIdx.x; i < 4 * CDIM; i += 1024) WsL[i] = wsb[OFF_WS + i];
    if (threadIdx.x < 4) ckL[threadIdx.x] = wsb[OFF_CK + threadIdx.x];
    __syncthreads();
    int w = threadIdx.x >> 6, lane = threadIdx.x & 63;
    int r = blockIdx.x * 16 + w;
    if (r >= BATCH * NTOK) return;
    int b = r / NTOK, n = r % NTOK;
    const float* row = (n == 0) ? t : x + ((size_t)b * NIN + (n - 1)) * CDIM;
    float a0 = 0.f, a1 = 0.f, a2 = 0.f, a3 = 0.f;
#pragma unroll
    for (int k = 0; k < 4; ++k) {
        int c0 = k * 256 + lane * 4;
        float4 xv = *(const float4*)(row + c0);
        float4 w0 = *(const float4*)&WsL[0 * CDIM + c0];
        float4 w1 = *(const float4*)&WsL[1 * CDIM + c0];
        float4 w2 = *(const float4*)&WsL[2 * CDIM + c0];
        float4 w3 = *(const float4*)&WsL[3 * CDIM + c0];
        a0 += xv.x * w0.x + xv.y * w0.y + xv.z * w0.z + xv.w * w0.w;
        a1 += xv.x * w1.x + xv.y * w1.y + xv.z * w1.z + xv.w * w1.w;
        a2 += xv.x * w2.x + xv.y * w2.y + xv.z * w2.z + xv.w * w2.w;
        a3 += xv.x * w3.x + xv.y * w3.y + xv.z * w3.z + xv.w * w3.w;
    }
    for (int off = 32; off > 0; off >>= 1) {
        a0 += __shfl_down(a0, off);
        a1 += __shfl_down(a1, off);
        a2 += __shfl_down(a2, off);
        a3 += __shfl_down(a3, off);
    }
    if (lane == 0) {
        const float scale = 0.0625f;   // Dh=256 -> 1/16
        wsb[OFF_SC + ((size_t)b * 4 + 0) * NTOK + n] = (a0 + ckL[0]) * scale;
        wsb[OFF_SC + ((size_t)b * 4 + 1) * NTOK + n] = (a1 + ckL[1]) * scale;
        wsb[OFF_SC + ((size_t)b * 4 + 2) * NTOK + n] = (a2 + ckL[2]) * scale;
        wsb[OFF_SC + ((size_t)b * 4 + 3) * NTOK + n] = (a3 + ckL[3]) * scale;
    }
}

// ---- softmax in place over n for each (b,h) ----
__global__ void k_softmax(float* __restrict__ wsb) {
    float* sc = wsb + OFF_SC + (size_t)blockIdx.x * NTOK;
    __shared__ float redM[4];
    __shared__ float redS[4];
    int tid = threadIdx.x, lane = tid & 63, w = tid >> 6;
    float m = -1e30f;
    for (int n = tid; n < NTOK; n += 256) m = fmaxf(m, sc[n]);
    for (int off = 32; off > 0; off >>= 1) m = fmaxf(m, __shfl_down(m, off));
    if (lane == 0) redM[w] = m;
    __syncthreads();
    m = fmaxf(fmaxf(redM[0], redM[1]), fmaxf(redM[2], redM[3]));
    float s = 0.f;
    for (int n = tid; n < NTOK; n += 256) s += expf(sc[n] - m);
    for (int off = 32; off > 0; off >>= 1) s += __shfl_down(s, off);
    if (lane == 0) redS[w] = s;
    __syncthreads();
    s = redS[0] + redS[1] + redS[2] + redS[3];
    float inv = 1.f / s;
    for (int n = tid; n < NTOK; n += 256) sc[n] = expf(sc[n] - m) * inv;
}

// ---- partial y: yp[b][ch][h][c] = sum_{n in chunk} att[b][h][n] * x_row[c] ----
__global__ void k_y(const float* __restrict__ x, const float* __restrict__ t,
                    float* __restrict__ wsb) {
    int b = blockIdx.x >> 5, ch = blockIdx.x & 31;
    int n0 = ch * 65;
    int nend = min(n0 + 65, NTOK);
    int cnt = nend - n0;
    __shared__ float attL[4][65];
    for (int idx = threadIdx.x; idx < 4 * 65; idx += 256) {
        int h = idx / 65, i = idx % 65;
        attL[h][i] = (i < cnt) ? wsb[OFF_SC + ((size_t)b * 4 + h) * NTOK + n0 + i] : 0.f;
    }
    __syncthreads();
    int c0 = threadIdx.x * 4;
    float4 acc[4];
#pragma unroll
    for (int h = 0; h < 4; ++h) acc[h] = make_float4(0.f, 0.f, 0.f, 0.f);
    for (int i = 0; i < cnt; ++i) {
        int n = n0 + i;
        const float* row = (n == 0) ? t : x + ((size_t)b * NIN + (n - 1)) * CDIM;
        float4 xv = *(const float4*)(row + c0);
#pragma unroll
        for (int h = 0; h < 4; ++h) {
            float a = attL[h][i];
            acc[h].x += a * xv.x; acc[h].y += a * xv.y;
            acc[h].z += a * xv.z; acc[h].w += a * xv.w;
        }
    }
#pragma unroll
    for (int h = 0; h < 4; ++h)
        *(float4*)&wsb[OFF_YP + ((size_t)(b * 32 + ch) * 4 + h) * CDIM + c0] = acc[h];
}

// ---- oc[b][c'] = sum_c y[b][h(c')][c] * Wqkv[c, 2C+c'] (+ bias when q==0) ----
__global__ void k_ocy(const float* __restrict__ W, const float* __restrict__ bqkv,
                      float* __restrict__ wsb) {
    int p = blockIdx.x >> 3, q = blockIdx.x & 7;   // p: c' chunk of 128, q: c chunk of 128
    int h = p >> 1;
    __shared__ float sL[1024];                     // y[b][c-slice], b-major
    for (int bb = 0; bb < 8; ++bb) {
        float sum = 0.f;
        for (int chn = 0; chn < 32; ++chn)
            sum += wsb[OFF_YP + ((size_t)(bb * 32 + chn) * 4 + h) * CDIM + q * 128 + threadIdx.x];
        sL[bb * 128 + threadIdx.x] = sum;
    }
    __syncthreads();
    int cp = p * 128 + threadIdx.x;
    float acc[8] = {0.f, 0.f, 0.f, 0.f, 0.f, 0.f, 0.f, 0.f};
    for (int c = 0; c < 128; ++c) {
        float wv = W[(size_t)(q * 128 + c) * TC + 2 * CDIM + cp];
#pragma unroll
        for (int bb = 0; bb < 8; ++bb) acc[bb] += sL[bb * 128 + c] * wv;
    }
    if (q == 0) {
        float bias = bqkv[2 * CDIM + cp];
#pragma unroll
        for (int bb = 0; bb < 8; ++bb) acc[bb] += bias;
    }
#pragma unroll
    for (int bb = 0; bb < 8; ++bb) atomicAdd(&wsb[OFF_OC + bb * CDIM + cp], acc[bb]);
}

// ---- out[b][j] = sum_c oc[b][c] * Wv[c, j] (+ bv when cq==0) ----
__global__ void k_out(const float* __restrict__ Wv, const float* __restrict__ bv,
                      const float* __restrict__ wsb, float* __restrict__ out) {
    int jp = blockIdx.x >> 3, cq = blockIdx.x & 7;
    __shared__ float ocL[1024];
    for (int bb = 0; bb < 8; ++bb)
        ocL[bb * 128 + threadIdx.x] = wsb[OFF_OC + bb * CDIM + cq * 128 + threadIdx.x];
    __syncthreads();
    int j = jp * 128 + threadIdx.x;
    float acc[8] = {0.f, 0.f, 0.f, 0.f, 0.f, 0.f, 0.f, 0.f};
    for (int c = 0; c < 128; ++c) {
        float wv = Wv[(size_t)(cq * 128 + c) * CDIM + j];
#pragma unroll
        for (int bb = 0; bb < 8; ++bb) acc[bb] += ocL[bb * 128 + c] * wv;
    }
    if (cq == 0) {
        float bias = bv[j];
#pragma unroll
        for (int bb = 0; bb < 8; ++bb) acc[bb] += bias;
    }
#pragma unroll
    for (int bb = 0; bb < 8; ++bb) atomicAdd(&out[bb * CDIM + j], acc[bb]);
}

extern "C" void kernel_launch(void* const* d_in, const int* in_sizes, int n_in,
                              void* d_out, int out_size, void* d_ws, size_t ws_size,
                              hipStream_t stream) {
    const float* x    = (const float*)d_in[0];   // [8,2048,1024]
    const float* t    = (const float*)d_in[1];   // [1,1,1024]
    const float* Wqkv = (const float*)d_in[2];   // [1024,3072]
    const float* bqkv = (const float*)d_in[3];   // [3072]
    const float* Wv   = (const float*)d_in[4];   // [1024,1024]
    const float* bv   = (const float*)d_in[5];   // [1024]
    float* wsb = (float*)d_ws;
    float* out = (float*)d_out;                  // [8,1024] fp32

    hipMemsetAsync(wsb, 0, ZERO_FLOATS * sizeof(float), stream);
    hipMemsetAsync(out, 0, (size_t)out_size * sizeof(float), stream);

    k_q0     <<<64,   128, 0, stream>>>(t, Wqkv, wsb);
    k_ws     <<<1024, 256, 0, stream>>>(Wqkv, bqkv, wsb);
    k_scores <<<1025, 1024, 0, stream>>>(x, t, wsb);
    k_softmax<<<32,   256, 0, stream>>>(wsb);
    k_y      <<<256,  256, 0, stream>>>(x, t, wsb);
    k_ocy    <<<64,   128, 0, stream>>>(Wqkv, bqkv, wsb);
    k_out    <<<64,   128, 0, stream>>>(Wv, bv, wsb, out);
}

// Round 2
// 182.189 us; speedup vs baseline: 1.0304x; 1.0304x over previous
//
#include <hip/hip_runtime.h>
#include <math.h>

#define CDIM 1024
#define TC   3072
#define BATCH 8
#define NIN   2048   // input rows per batch (class token handled separately)
#define NHEAD 4

// workspace float offsets
#define OFF_Q0 0                 // 1024 (zeroed)
#define OFF_OC 1024              // 8192 (zeroed)
#define ZERO_FLOATS 9216
#define OFF_WS 9216              // 4*1024  [h][c]
#define OFF_PM 13312             // 512*4   per-block online-softmax max
#define OFF_PS 15360             // 512*4   per-block exp-sum
#define OFF_PY 17408             // 512*4*1024 partial weighted x-sums
#define OFF_YB 2114560           // 8*4*1024 final attention-averaged rows

// ---- q0 partial: q0[j] = sum_i t[i] * Wqkv[i, j] (Q columns; bias added in k_ws) ----
__global__ void k_q0(const float* __restrict__ t, const float* __restrict__ W,
                     float* __restrict__ wsb) {
    int ic = blockIdx.x >> 3, jc = blockIdx.x & 7;   // 32 i-chunks x 8 j-chunks
    int j = jc * 128 + threadIdx.x;
    int i0 = ic * 32;
    float acc = 0.f;
    for (int i = 0; i < 32; ++i)
        acc += t[i0 + i] * W[(size_t)(i0 + i) * TC + j];
    atomicAdd(&wsb[OFF_Q0 + j], acc);
}

// ---- Ws[h][c] = sum_d Wk[c, h*256+d] * (q0[h*256+d] + bq[h*256+d]) ----
__global__ void k_ws(const float* __restrict__ W, const float* __restrict__ bqkv,
                     float* __restrict__ wsb) {
    int wave = threadIdx.x >> 6, lane = threadIdx.x & 63;
    int gw = blockIdx.x * 4 + wave;        // 4096 waves: (c,h)
    int c = gw >> 2, h = gw & 3;
    int d0 = h * 256 + lane * 4;
    float4 wv = *(const float4*)&W[(size_t)c * TC + CDIM + d0];
    float q0 = wsb[OFF_Q0 + d0]     + bqkv[d0];
    float q1 = wsb[OFF_Q0 + d0 + 1] + bqkv[d0 + 1];
    float q2 = wsb[OFF_Q0 + d0 + 2] + bqkv[d0 + 2];
    float q3 = wsb[OFF_Q0 + d0 + 3] + bqkv[d0 + 3];
    float acc = wv.x * q0 + wv.y * q1 + wv.z * q2 + wv.w * q3;
    for (int off = 32; off > 0; off >>= 1) acc += __shfl_down(acc, off);
    if (lane == 0) wsb[OFF_WS + h * CDIM + c] = acc;
}

// ---- single pass over X: scores + online softmax + weighted row-sum, all fused ----
// 512 blocks x 256 thr; block = (b, 32-row chunk); wave owns 8 consecutive rows.
__global__ __launch_bounds__(256) void k_pass1(const float* __restrict__ x,
                                               float* __restrict__ wsb) {
    int tid = threadIdx.x, lane = tid & 63, wave = tid >> 6;
    int b = blockIdx.x >> 6, blkc = blockIdx.x & 63;

    // Ws in registers: wsr[k][h] covers c = k*256 + lane*4 .. +3
    float4 wsr[4][4];
#pragma unroll
    for (int k = 0; k < 4; ++k)
#pragma unroll
        for (int h = 0; h < 4; ++h)
            wsr[k][h] = *(const float4*)&wsb[OFF_WS + h * CDIM + k * 256 + lane * 4];

    float m[4], s[4];
    float4 y[4][4];
#pragma unroll
    for (int h = 0; h < 4; ++h) {
        m[h] = -1e30f; s[h] = 0.f;
#pragma unroll
        for (int k = 0; k < 4; ++k) y[h][k] = make_float4(0.f, 0.f, 0.f, 0.f);
    }

    const float* base = x + ((size_t)b * NIN + blkc * 32 + wave * 8) * CDIM;
#pragma unroll 2
    for (int i = 0; i < 8; ++i) {
        const float* row = base + (size_t)i * CDIM;
        float4 xv[4];
#pragma unroll
        for (int k = 0; k < 4; ++k) xv[k] = *(const float4*)&row[k * 256 + lane * 4];
        float d[4];
#pragma unroll
        for (int h = 0; h < 4; ++h) {
            float a = 0.f;
#pragma unroll
            for (int k = 0; k < 4; ++k)
                a += xv[k].x * wsr[k][h].x + xv[k].y * wsr[k][h].y +
                     xv[k].z * wsr[k][h].z + xv[k].w * wsr[k][h].w;
            // butterfly: all lanes end with the full 64-lane sum
            for (int off = 1; off < 64; off <<= 1) a += __shfl_xor(a, off);
            d[h] = a * 0.0625f;   // Dh=256 -> scale 1/16; per-head +ck cancels in softmax
        }
#pragma unroll
        for (int h = 0; h < 4; ++h) {
            float sc = d[h], f;
            if (sc > m[h]) {              // wave-uniform branch
                float rs = __expf(m[h] - sc);
                s[h] *= rs;
#pragma unroll
                for (int k = 0; k < 4; ++k) {
                    y[h][k].x *= rs; y[h][k].y *= rs; y[h][k].z *= rs; y[h][k].w *= rs;
                }
                m[h] = sc; f = 1.f;
            } else f = __expf(sc - m[h]);
            s[h] += f;
#pragma unroll
            for (int k = 0; k < 4; ++k) {
                y[h][k].x += f * xv[k].x; y[h][k].y += f * xv[k].y;
                y[h][k].z += f * xv[k].z; y[h][k].w += f * xv[k].w;
            }
        }
    }

    // block merge of 4 wave states via LDS
    __shared__ float ms[4][4], ss[4][4];
    __shared__ float ybuf[4][CDIM];
    if (lane == 0)
#pragma unroll
        for (int h = 0; h < 4; ++h) { ms[wave][h] = m[h]; ss[wave][h] = s[h]; }
    for (int idx = tid; idx < 4 * CDIM; idx += 256) ((float*)ybuf)[idx] = 0.f;
    __syncthreads();
    float mb[4], sb[4], fme[4];
#pragma unroll
    for (int h = 0; h < 4; ++h) {
        mb[h] = fmaxf(fmaxf(ms[0][h], ms[1][h]), fmaxf(ms[2][h], ms[3][h]));
        sb[h] = 0.f;
#pragma unroll
        for (int w = 0; w < 4; ++w) sb[h] += __expf(ms[w][h] - mb[h]) * ss[w][h];
        fme[h] = __expf(m[h] - mb[h]);
    }
    for (int w = 0; w < 4; ++w) {
        if (wave == w) {
#pragma unroll
            for (int h = 0; h < 4; ++h)
#pragma unroll
                for (int k = 0; k < 4; ++k) {
                    float4* dst = (float4*)&ybuf[h][k * 256 + lane * 4];
                    float4 v = *dst;
                    v.x += fme[h] * y[h][k].x; v.y += fme[h] * y[h][k].y;
                    v.z += fme[h] * y[h][k].z; v.w += fme[h] * y[h][k].w;
                    *dst = v;
                }
        }
        __syncthreads();
    }
    int p = blockIdx.x;
    if (tid < 4) { wsb[OFF_PM + p * 4 + tid] = mb[tid]; wsb[OFF_PS + p * 4 + tid] = sb[tid]; }
    for (int idx = tid; idx < 4 * CDIM; idx += 256)
        wsb[OFF_PY + (size_t)p * 4096 + idx] = ((float*)ybuf)[idx];
}

// ---- combine 64 chunk-partials per (b,h) + class-token term -> ybar[b][h][c] ----
// grid 128 = (b, h, cq); each thread owns one c in its 256-wide cq slice.
__global__ void k_comb(const float* __restrict__ t, float* __restrict__ wsb) {
    int tid = threadIdx.x, lane = tid & 63, wv = tid >> 6;
    int blk = blockIdx.x;
    int b = blk >> 4, h = (blk >> 2) & 3, cq = blk & 3;
    __shared__ float red[4], redM[4], redS[4], fbuf[64];

    // sc0 = (t . Ws_h) / 16  (same dropped-+ck convention as k_pass1)
    int c0 = tid * 4;
    float4 tv = *(const float4*)&t[c0];
    float4 wsv = *(const float4*)&wsb[OFF_WS + h * CDIM + c0];
    float p = tv.x * wsv.x + tv.y * wsv.y + tv.z * wsv.z + tv.w * wsv.w;
    for (int off = 1; off < 64; off <<= 1) p += __shfl_xor(p, off);
    if (lane == 0) red[wv] = p;
    __syncthreads();
    float sc0 = (red[0] + red[1] + red[2] + red[3]) * 0.0625f;

    float mv = (tid < 64) ? wsb[OFF_PM + (size_t)(b * 64 + tid) * 4 + h] : -1e30f;
    float mr = mv;
    for (int off = 1; off < 64; off <<= 1) mr = fmaxf(mr, __shfl_xor(mr, off));
    if (lane == 0) redM[wv] = mr;
    __syncthreads();
    float M = fmaxf(fmaxf(fmaxf(redM[0], redM[1]), fmaxf(redM[2], redM[3])), sc0);

    float sv = 0.f;
    if (tid < 64) {
        float fj = __expf(mv - M);
        fbuf[tid] = fj;
        sv = fj * wsb[OFF_PS + (size_t)(b * 64 + tid) * 4 + h];
    }
    for (int off = 1; off < 64; off <<= 1) sv += __shfl_xor(sv, off);
    if (lane == 0) redS[wv] = sv;
    __syncthreads();
    float e0 = __expf(sc0 - M);
    float S = redS[0] + redS[1] + redS[2] + redS[3] + e0;

    int c = cq * 256 + tid;
    float acc = e0 * t[c];
    for (int j = 0; j < 64; ++j)
        acc += fbuf[j] * wsb[OFF_PY + (size_t)(b * 64 + j) * 4096 + h * CDIM + c];
    wsb[OFF_YB + (size_t)(b * 4 + h) * CDIM + c] = acc / S;
}

// ---- oc[b][c'] = ybar[b][h(c')] . Wqkv[:, 2C+c'] + bias ----
__global__ void k_ocy(const float* __restrict__ W, const float* __restrict__ bqkv,
                      float* __restrict__ wsb) {
    int p = blockIdx.x >> 3, q = blockIdx.x & 7;
    int h = p >> 1;
    __shared__ float sL[1024];
    for (int bb = 0; bb < 8; ++bb)
        sL[bb * 128 + threadIdx.x] = wsb[OFF_YB + (size_t)(bb * 4 + h) * CDIM + q * 128 + threadIdx.x];
    __syncthreads();
    int cp = p * 128 + threadIdx.x;
    float acc[8] = {0.f, 0.f, 0.f, 0.f, 0.f, 0.f, 0.f, 0.f};
    for (int c = 0; c < 128; ++c) {
        float wv = W[(size_t)(q * 128 + c) * TC + 2 * CDIM + cp];
#pragma unroll
        for (int bb = 0; bb < 8; ++bb) acc[bb] += sL[bb * 128 + c] * wv;
    }
    if (q == 0) {
        float bias = bqkv[2 * CDIM + cp];
#pragma unroll
        for (int bb = 0; bb < 8; ++bb) acc[bb] += bias;
    }
#pragma unroll
    for (int bb = 0; bb < 8; ++bb) atomicAdd(&wsb[OFF_OC + bb * CDIM + cp], acc[bb]);
}

// ---- out[b][j] = oc[b] . Wv[:, j] + bv ----
__global__ void k_out(const float* __restrict__ Wv, const float* __restrict__ bv,
                      const float* __restrict__ wsb, float* __restrict__ out) {
    int jp = blockIdx.x >> 3, cq = blockIdx.x & 7;
    __shared__ float ocL[1024];
    for (int bb = 0; bb < 8; ++bb)
        ocL[bb * 128 + threadIdx.x] = wsb[OFF_OC + bb * CDIM + cq * 128 + threadIdx.x];
    __syncthreads();
    int j = jp * 128 + threadIdx.x;
    float acc[8] = {0.f, 0.f, 0.f, 0.f, 0.f, 0.f, 0.f, 0.f};
    for (int c = 0; c < 128; ++c) {
        float wv = Wv[(size_t)(cq * 128 + c) * CDIM + j];
#pragma unroll
        for (int bb = 0; bb < 8; ++bb) acc[bb] += ocL[bb * 128 + c] * wv;
    }
    if (cq == 0) {
        float bias = bv[j];
#pragma unroll
        for (int bb = 0; bb < 8; ++bb) acc[bb] += bias;
    }
#pragma unroll
    for (int bb = 0; bb < 8; ++bb) atomicAdd(&out[bb * CDIM + j], acc[bb]);
}

extern "C" void kernel_launch(void* const* d_in, const int* in_sizes, int n_in,
                              void* d_out, int out_size, void* d_ws, size_t ws_size,
                              hipStream_t stream) {
    const float* x    = (const float*)d_in[0];   // [8,2048,1024]
    const float* t    = (const float*)d_in[1];   // [1,1,1024]
    const float* Wqkv = (const float*)d_in[2];   // [1024,3072]
    const float* bqkv = (const float*)d_in[3];   // [3072]
    const float* Wv   = (const float*)d_in[4];   // [1024,1024]
    const float* bv   = (const float*)d_in[5];   // [1024]
    float* wsb = (float*)d_ws;
    float* out = (float*)d_out;                  // [8,1024] fp32

    hipMemsetAsync(wsb, 0, ZERO_FLOATS * sizeof(float), stream);
    hipMemsetAsync(out, 0, (size_t)out_size * sizeof(float), stream);

    k_q0   <<<256,  128, 0, stream>>>(t, Wqkv, wsb);
    k_ws   <<<1024, 256, 0, stream>>>(Wqkv, bqkv, wsb);
    k_pass1<<<512,  256, 0, stream>>>(x, wsb);
    k_comb <<<128,  256, 0, stream>>>(t, wsb);
    k_ocy  <<<64,   128, 0, stream>>>(Wqkv, bqkv, wsb);
    k_out  <<<64,   128, 0, stream>>>(Wv, bv, wsb, out);
}